// Round 5
// baseline (3996.548 us; speedup 1.0000x reference)
//
#include <hip/hip_runtime.h>
#include <hip/hip_bf16.h>

#define HID   512
#define SEQ   1024
#define GATES 2048       // 4*HID

// ---------------------------------------------------------------- helpers
__device__ __forceinline__ float sigm(float x) {
    return 1.f / (1.f + __expf(-x));
}
__device__ __forceinline__ float tanh_fast(float x) {
    float ax = fabsf(x);
    float e  = __expf(-2.f * ax);
    float t  = (1.f - e) * __builtin_amdgcn_rcpf(1.f + e);
    return copysignf(t, x);
}
__device__ __forceinline__ float bcast(float v, int l) {
    return __uint_as_float((unsigned)__builtin_amdgcn_readlane((int)__float_as_uint(v), l));
}
// nontemporal 16B load (ext_vector_type is a real vector type, accepted by the builtin)
typedef float floatx4 __attribute__((ext_vector_type(4)));
__device__ __forceinline__ floatx4 ntload4(const float* p) {
    return __builtin_nontemporal_load((const floatx4*)p);
}
// acquire-poll a tile counter until all 32 n-tiles of an m-block are done.
// GEMM blocks in the same kernel are dependency-free, so this always terminates.
__device__ __forceinline__ void wait_tiles32(const unsigned* c) {
    while (__hip_atomic_load(c, __ATOMIC_ACQUIRE, __HIP_MEMORY_SCOPE_AGENT) != 32u) {}
}

// ---------------------------------------------------------------- embedding (+ per-launch counter reset)
__global__ void embed_kernel(const int* __restrict__ wi, const int* __restrict__ pi,
                             const float* __restrict__ we, const float* __restrict__ pe,
                             float* __restrict__ x, unsigned* __restrict__ cnt) {
    if (blockIdx.x == 0 && threadIdx.x < 32) cnt[threadIdx.x] = 0u;  // cntA[16] + cntB[16]
    int i = blockIdx.x;          // token 0..1023
    int t = threadIdx.x;         // 128 threads
    const float* w = we + (size_t)wi[i] * 300;
    const float* p = pe + (size_t)pi[i] * 100;
    float* xo = x + (size_t)i * 400;
    for (int c = t; c < 300; c += 128) xo[c]       = w[c];
    for (int c = t; c < 100; c += 128) xo[300 + c] = p[c];
}

// ---------------------------------------------------------------- fp32 GEMM pair, 128x64 tile (standalone, for the head/dep projection)
__global__ __launch_bounds__(256)
void gemm_bias2(const float* __restrict__ A,
                const float* __restrict__ B0, const float* __restrict__ bias0, float* __restrict__ C0,
                const float* __restrict__ B1, const float* __restrict__ bias1, float* __restrict__ C1,
                int M, int N, int K, int lda, int ldb, int ldc) {
    const float* B    = blockIdx.z ? B1    : B0;
    const float* bias = blockIdx.z ? bias1 : bias0;
    float*       C    = blockIdx.z ? C1    : C0;

    __shared__ __align__(16) float As[16 * 132];
    __shared__ __align__(16) float Bs[16 * 68];
    const int tid  = threadIdx.x;
    const int bn   = blockIdx.x, bm = blockIdx.y;
    const int tj   = tid & 15, ti = tid >> 4;
    const int arow = tid >> 1;               // 0..127
    const int ak8  = (tid & 1) * 8;          // 0 or 8
    const int brow = tid >> 2;               // 0..63
    const int bk4  = (tid & 3) * 4;          // 0,4,8,12
    float acc[8][4] = {};

    for (int kt = 0; kt < K; kt += 16) {
        float4 a0 = *(const float4*)(A + (size_t)(bm * 128 + arow) * lda + kt + ak8);
        float4 a1 = *(const float4*)(A + (size_t)(bm * 128 + arow) * lda + kt + ak8 + 4);
        float4 bv = *(const float4*)(B + (size_t)(bn * 64 + brow) * ldb + kt + bk4);
        As[(ak8 + 0) * 132 + arow] = a0.x; As[(ak8 + 1) * 132 + arow] = a0.y;
        As[(ak8 + 2) * 132 + arow] = a0.z; As[(ak8 + 3) * 132 + arow] = a0.w;
        As[(ak8 + 4) * 132 + arow] = a1.x; As[(ak8 + 5) * 132 + arow] = a1.y;
        As[(ak8 + 6) * 132 + arow] = a1.z; As[(ak8 + 7) * 132 + arow] = a1.w;
        Bs[(bk4 + 0) * 68 + brow] = bv.x; Bs[(bk4 + 1) * 68 + brow] = bv.y;
        Bs[(bk4 + 2) * 68 + brow] = bv.z; Bs[(bk4 + 3) * 68 + brow] = bv.w;
        __syncthreads();
        #pragma unroll
        for (int k = 0; k < 16; ++k) {
            float4 x0 = *(const float4*)&As[k * 132 + ti * 8];
            float4 x1 = *(const float4*)&As[k * 132 + ti * 8 + 4];
            float4 b4 = *(const float4*)&Bs[k * 68 + tj * 4];
            const float av[8] = {x0.x, x0.y, x0.z, x0.w, x1.x, x1.y, x1.z, x1.w};
            #pragma unroll
            for (int i = 0; i < 8; ++i) {
                acc[i][0] = fmaf(av[i], b4.x, acc[i][0]);
                acc[i][1] = fmaf(av[i], b4.y, acc[i][1]);
                acc[i][2] = fmaf(av[i], b4.z, acc[i][2]);
                acc[i][3] = fmaf(av[i], b4.w, acc[i][3]);
            }
        }
        __syncthreads();
    }
    const int n0 = bn * 64 + tj * 4;
    float bb0 = 0.f, bb1 = 0.f, bb2 = 0.f, bb3 = 0.f;
    if (bias) { bb0 = bias[n0]; bb1 = bias[n0 + 1]; bb2 = bias[n0 + 2]; bb3 = bias[n0 + 3]; }
    #pragma unroll
    for (int i = 0; i < 8; ++i) {
        float4 o;
        o.x = acc[i][0] + bb0; o.y = acc[i][1] + bb1;
        o.z = acc[i][2] + bb2; o.w = acc[i][3] + bb3;
        *(float4*)(C + (size_t)(bm * 128 + ti * 8 + i) * ldc + n0) = o;
    }
}

// ---------------------------------------------------------------- fused: input-projection GEMM + persistent bidirectional LSTM layer
// R10: 128 blocks x 576 threads (was 256 in R9-fused; throttled to discriminate
// and avoid CU co-residency with the LSTM blocks). Blocks [0,64): LSTM (R8
// mechanics + 3-deep poll). Blocks [64,128): 64 GEMM blocks, looping over 512
// tiles in priority order (level L = fwd m-block L + rev m-block 7-L); weight
// and activation streams use nontemporal loads to stay out of the caches the
// poll path uses. Deadlock-free: 128 blocks always co-resident; GEMM blocks
// never wait in-kernel.
__global__ __launch_bounds__(576)
void lstm_fused(const float* __restrict__ Zf, const float* __restrict__ Zr,
                const float* __restrict__ WhhF, const float* __restrict__ WhhR,
                unsigned long long* __restrict__ Hpair, // [SEQ][2*HID] (tag|h)
                float* __restrict__ Hout,               // [SEQ][2*HID] plain fp32
                unsigned tagBase,
                const float* __restrict__ Ag,           // GEMM input [1024 x K]
                const float* __restrict__ Bg0, const float* __restrict__ bg0, float* __restrict__ Cg0,
                const float* __restrict__ Bg1, const float* __restrict__ bg1, float* __restrict__ Cg1,
                int K, int ldab,
                unsigned* __restrict__ cnt) {            // [2][8] tile counters
    __shared__ __align__(16) float As[16 * 132];
    __shared__ __align__(16) float Bs[16 * 68];
    __shared__ float part[2][8 * 65];

    const int b   = blockIdx.x;
    const int tid = threadIdx.x;

    if (b >= 64) {
        // ================= GEMM role =================
        const int gb  = b - 64;          // 0..63
        const bool act = tid < 256;
        const int tj   = tid & 15, ti = tid >> 4;
        const int arow = tid >> 1;       // 0..127 when act
        const int ak8  = (tid & 1) * 8;
        const int brow = tid >> 2;       // 0..63 when act
        const int bk4  = (tid & 3) * 4;
        for (int o = gb; o < 512; o += 64) {
            // priority order: level L serves fwd m-block L (zA) and rev m-block 7-L (zB)
            const int level = o >> 6;
            const int half  = (o >> 5) & 1;
            const int bn    = o & 31;
            const int bz    = half;
            const int bm    = half ? (7 - level) : level;
            const float* Bm   = bz ? Bg1 : Bg0;
            const float* bias = bz ? bg1 : bg0;
            float*       C    = bz ? Cg1 : Cg0;
            float acc[8][4] = {};
            for (int kt = 0; kt < K; kt += 16) {
                if (act) {
                    floatx4 a0 = ntload4(Ag + (size_t)(bm * 128 + arow) * ldab + kt + ak8);
                    floatx4 a1 = ntload4(Ag + (size_t)(bm * 128 + arow) * ldab + kt + ak8 + 4);
                    floatx4 bv = ntload4(Bm + (size_t)(bn * 64 + brow) * ldab + kt + bk4);
                    As[(ak8 + 0) * 132 + arow] = a0.x; As[(ak8 + 1) * 132 + arow] = a0.y;
                    As[(ak8 + 2) * 132 + arow] = a0.z; As[(ak8 + 3) * 132 + arow] = a0.w;
                    As[(ak8 + 4) * 132 + arow] = a1.x; As[(ak8 + 5) * 132 + arow] = a1.y;
                    As[(ak8 + 6) * 132 + arow] = a1.z; As[(ak8 + 7) * 132 + arow] = a1.w;
                    Bs[(bk4 + 0) * 68 + brow] = bv.x; Bs[(bk4 + 1) * 68 + brow] = bv.y;
                    Bs[(bk4 + 2) * 68 + brow] = bv.z; Bs[(bk4 + 3) * 68 + brow] = bv.w;
                }
                __syncthreads();
                if (act) {
                    #pragma unroll
                    for (int k = 0; k < 16; ++k) {
                        float4 x0 = *(const float4*)&As[k * 132 + ti * 8];
                        float4 x1 = *(const float4*)&As[k * 132 + ti * 8 + 4];
                        float4 b4 = *(const float4*)&Bs[k * 68 + tj * 4];
                        const float av[8] = {x0.x, x0.y, x0.z, x0.w, x1.x, x1.y, x1.z, x1.w};
                        #pragma unroll
                        for (int i = 0; i < 8; ++i) {
                            acc[i][0] = fmaf(av[i], b4.x, acc[i][0]);
                            acc[i][1] = fmaf(av[i], b4.y, acc[i][1]);
                            acc[i][2] = fmaf(av[i], b4.z, acc[i][2]);
                            acc[i][3] = fmaf(av[i], b4.w, acc[i][3]);
                        }
                    }
                }
                __syncthreads();
            }
            if (act) {
                const int n0 = bn * 64 + tj * 4;
                float bb0 = 0.f, bb1 = 0.f, bb2 = 0.f, bb3 = 0.f;
                if (bias) { bb0 = bias[n0]; bb1 = bias[n0 + 1]; bb2 = bias[n0 + 2]; bb3 = bias[n0 + 3]; }
                #pragma unroll
                for (int i = 0; i < 8; ++i) {
                    float4 ov;
                    ov.x = acc[i][0] + bb0; ov.y = acc[i][1] + bb1;
                    ov.z = acc[i][2] + bb2; ov.w = acc[i][3] + bb3;
                    *(float4*)(C + (size_t)(bm * 128 + ti * 8 + i) * 2048 + n0) = ov;
                }
            }
            __syncthreads();   // all tile stores issued before publish
            if (tid == 0)
                __hip_atomic_fetch_add(&cnt[bz * 8 + bm], 1u,
                                       __ATOMIC_RELEASE, __HIP_MEMORY_SCOPE_AGENT);
        }
        return;
    }

    // ================= LSTM role (R8 mechanics + 3-deep poll) =================
    const int dir = b >> 5;
    const int wg  = b & 31;
    const float* __restrict__ Z   = dir ? Zr   : Zf;
    const float* __restrict__ Whh = dir ? WhhR : WhhF;
    const int colOff = dir ? HID : 0;

    const int wave = tid >> 6;        // 0 = producer; 1..8 = k-chunks
    const int lane = tid & 63;        // local gate row 0..63
    const int g    = lane >> 4;       // gate 0..3 (i,f,g,o)
    const int jj   = lane & 15;       // local hidden unit 0..15
    const int grow = g * HID + wg * 16 + jj;   // row in Whh [2048 x 512]

    if (wave == 0) {
        // ---------------- producer / finisher wave ----------------
        const unsigned* zcnt = cnt + dir * 8;
        float cval = 0.f;                 // cell state (lanes 0..15)
        const int t0 = dir ? (SEQ - 1) : 0;
        wait_tiles32(zcnt + (t0 >> 7));   // gate on first m-block of z
        float zin = Z[(size_t)t0 * GATES + grow];
        for (int s = 0; s < SEQ; ++s) {
            const int t = dir ? (SEQ - 1 - s) : s;
            float znxt = 0.f;
            if (s + 1 < SEQ) {
                const int tn = dir ? (SEQ - 2 - s) : (s + 1);
                if ((tn & 127) == (dir ? 127 : 0)) wait_tiles32(zcnt + (tn >> 7));
                znxt = Z[(size_t)tn * GATES + grow];
            }
            __syncthreads();   // partials of step s are ready
            const float* pp = part[s & 1];
            float r = zin;
            #pragma unroll
            for (int c = 0; c < 8; ++c) r += pp[c * 65 + lane];
            float nl = (g == 2) ? tanh_fast(r) : sigm(r);
            float ig = __shfl(nl, jj);
            float fg = __shfl(nl, 16 + jj);
            float gg = __shfl(nl, 32 + jj);
            float og = __shfl(nl, 48 + jj);
            if (lane < 16) {
                cval = fg * cval + ig * gg;
                float hv = og * tanh_fast(cval);
                const size_t oidx = (size_t)t * (2 * HID) + colOff + wg * 16 + lane;
                unsigned long long pk = ((unsigned long long)(tagBase + (unsigned)s) << 32)
                                      | (unsigned long long)__float_as_uint(hv);
                __hip_atomic_store(Hpair + oidx, pk, __ATOMIC_RELAXED, __HIP_MEMORY_SCOPE_AGENT);
                Hout[oidx] = hv;   // plain fp32 for downstream GEMMs (off critical path)
            }
            zin = znxt;
        }
    } else {
        // ---------------- matvec waves (k-chunks) ----------------
        const int kc = wave - 1;          // k-chunk 0..7 (h[64*kc .. +64))
        float w[64];
        {
            const float4* wp = (const float4*)(Whh + (size_t)grow * HID + kc * 64);
            #pragma unroll
            for (int q = 0; q < 16; ++q) {
                float4 v = wp[q];
                w[4 * q] = v.x; w[4 * q + 1] = v.y; w[4 * q + 2] = v.z; w[4 * q + 3] = v.w;
            }
        }
        for (int s = 0; s < SEQ; ++s) {
            const int t = dir ? (SEQ - 1 - s) : s;
            float acc = 0.f;
            if (s > 0) {
                const int tp = dir ? (t + 1) : (t - 1);
                const unsigned expTag = tagBase + (unsigned)s - 1u;
                const unsigned long long* hp =
                    Hpair + (size_t)tp * (2 * HID) + colOff + kc * 64 + lane;
                // 3-deep pipelined poll: oldest-of-three rotation; compiler
                // waits vmcnt(2) -> check period ~ latency/3
                unsigned long long va, vb, vc, v;
                va = __hip_atomic_load(hp, __ATOMIC_RELAXED, __HIP_MEMORY_SCOPE_AGENT);
                vb = __hip_atomic_load(hp, __ATOMIC_RELAXED, __HIP_MEMORY_SCOPE_AGENT);
                for (;;) {
                    vc = __hip_atomic_load(hp, __ATOMIC_RELAXED, __HIP_MEMORY_SCOPE_AGENT);
                    if (__all((unsigned)(va >> 32) == expTag)) { v = va; break; }
                    va = vb; vb = vc;
                }
                float hv = __uint_as_float((unsigned)v);   // h[64*kc + lane]
                float a0 = 0.f, a1 = 0.f, a2 = 0.f, a3 = 0.f;
                #pragma unroll
                for (int m = 0; m < 64; m += 4) {
                    a0 = fmaf(w[m + 0], bcast(hv, m + 0), a0);
                    a1 = fmaf(w[m + 1], bcast(hv, m + 1), a1);
                    a2 = fmaf(w[m + 2], bcast(hv, m + 2), a2);
                    a3 = fmaf(w[m + 3], bcast(hv, m + 3), a3);
                }
                acc = (a0 + a1) + (a2 + a3);
            }
            part[s & 1][kc * 65 + lane] = acc;
            __syncthreads();
        }
    }
}

// ---------------------------------------------------------------- pairwise MLP scores
__global__ __launch_bounds__(256)
void pairwise_kernel(const float* __restrict__ Ah, const float* __restrict__ Bd,
                     const float* __restrict__ w2, const float* __restrict__ b2,
                     float* __restrict__ out) {
    __shared__ __align__(16) float at[16 * 260];
    __shared__ __align__(16) float bt[16 * 260];
    __shared__ __align__(16) float wl[256];
    const int tid = threadIdx.x;
    const int i0 = blockIdx.y * 16, j0 = blockIdx.x * 16;
    for (int u = tid; u < 16 * 256; u += 256) {
        int r = u >> 8, m = u & 255;
        at[r * 260 + m] = Ah[(size_t)(i0 + r) * 256 + m];
        bt[r * 260 + m] = Bd[(size_t)(j0 + r) * 256 + m];
    }
    wl[tid] = w2[tid];
    __syncthreads();
    const int tj = tid & 15, ti = tid >> 4;
    float acc = b2[0];
    #pragma unroll 2
    for (int m = 0; m < 256; m += 4) {
        float4 a4 = *(const float4*)&at[ti * 260 + m];
        float4 b4 = *(const float4*)&bt[tj * 260 + m];
        float4 w4 = *(const float4*)&wl[m];
        acc += tanh_fast(a4.x + b4.x) * w4.x;
        acc += tanh_fast(a4.y + b4.y) * w4.y;
        acc += tanh_fast(a4.z + b4.z) * w4.z;
        acc += tanh_fast(a4.w + b4.w) * w4.w;
    }
    out[(size_t)(i0 + ti) * 1024 + (j0 + tj)] = acc;
}

// ---------------------------------------------------------------- launch
extern "C" void kernel_launch(void* const* d_in, const int* in_sizes, int n_in,
                              void* d_out, int out_size, void* d_ws, size_t ws_size,
                              hipStream_t stream) {
    const int*   wi    = (const int*)  d_in[0];
    const int*   pi    = (const int*)  d_in[1];
    const float* we    = (const float*)d_in[2];
    const float* pe    = (const float*)d_in[3];
    const float* wih0f = (const float*)d_in[4];
    const float* whh0f = (const float*)d_in[5];
    const float* b0f   = (const float*)d_in[6];
    const float* wih0r = (const float*)d_in[7];
    const float* whh0r = (const float*)d_in[8];
    const float* b0r   = (const float*)d_in[9];
    const float* wih1f = (const float*)d_in[10];
    const float* whh1f = (const float*)d_in[11];
    const float* b1f   = (const float*)d_in[12];
    const float* wih1r = (const float*)d_in[13];
    const float* whh1r = (const float*)d_in[14];
    const float* b1r   = (const float*)d_in[15];
    const float* W1    = (const float*)d_in[16];
    const float* bmlp1 = (const float*)d_in[17];
    const float* w2    = (const float*)d_in[18];
    const float* b2    = (const float*)d_in[19];
    float* out = (float*)d_out;

    char* wsb = (char*)d_ws;
    unsigned* cnt = (unsigned*)wsb;           // 32 u32: cntA = cnt, cntB = cnt+16
    float* x  = (float*)(wsb + 512);          // 1024*400
    float* zA = x  + (size_t)1024 * 400;      // 1024*2048
    float* zB = zA + (size_t)1024 * 2048;     // 1024*2048
    float* h0 = zB + (size_t)1024 * 2048;     // 1024*1024
    float* h1 = h0 + (size_t)1024 * 1024;     // 1024*1024
    float* aH = h1 + (size_t)1024 * 1024;     // 1024*256
    float* bD = aH + (size_t)1024 * 256;      // 1024*256
    unsigned long long* Hpair = (unsigned long long*)(bD + (size_t)1024 * 256); // 1024*1024 u64

    embed_kernel<<<dim3(1024), dim3(128), 0, stream>>>(wi, pi, we, pe, x, cnt);

    // layer 0: input projections fused with the recurrence
    lstm_fused<<<dim3(128), dim3(576), 0, stream>>>(
        zA, zB, whh0f, whh0r, Hpair, h0, 1u,
        x, wih0f, b0f, zA, wih0r, b0r, zB, 400, 400, cnt);

    // layer 1: input projections fused with the recurrence
    lstm_fused<<<dim3(128), dim3(576), 0, stream>>>(
        zA, zB, whh1f, whh1r, Hpair, h1, 8192u,
        h0, wih1f, b1f, zA, wih1r, b1r, zB, 1024, 1024, cnt + 16);

    // head/dep projections (one launch): [1024,1024]@[256,1024]^T (bmlp1 folded into aH)
    gemm_bias2<<<dim3(4, 8, 2), dim3(256), 0, stream>>>(
        h1, W1, bmlp1, aH, W1 + 1024, nullptr, bD, 1024, 256, 1024, 1024, 2048, 256);

    pairwise_kernel<<<dim3(64, 64), dim3(256), 0, stream>>>(aH, bD, w2, b2, out);
}

// Round 6
// 3950.391 us; speedup vs baseline: 1.0117x; 1.0117x over previous
//
#include <hip/hip_runtime.h>
#include <hip/hip_bf16.h>

#define HID   512
#define SEQ   1024
#define GATES 2048       // 4*HID

// ---------------------------------------------------------------- helpers
__device__ __forceinline__ float sigm(float x) {
    return 1.f / (1.f + __expf(-x));
}
__device__ __forceinline__ float tanh_fast(float x) {
    float ax = fabsf(x);
    float e  = __expf(-2.f * ax);
    float t  = (1.f - e) * __builtin_amdgcn_rcpf(1.f + e);
    return copysignf(t, x);
}
__device__ __forceinline__ float bcast(float v, int l) {
    return __uint_as_float((unsigned)__builtin_amdgcn_readlane((int)__float_as_uint(v), l));
}

// ---------------------------------------------------------------- embedding
__global__ void embed_kernel(const int* __restrict__ wi, const int* __restrict__ pi,
                             const float* __restrict__ we, const float* __restrict__ pe,
                             float* __restrict__ x) {
    int i = blockIdx.x;          // token 0..1023
    int t = threadIdx.x;         // 128 threads
    const float* w = we + (size_t)wi[i] * 300;
    const float* p = pe + (size_t)pi[i] * 100;
    float* xo = x + (size_t)i * 400;
    for (int c = t; c < 300; c += 128) xo[c]       = w[c];
    for (int c = t; c < 100; c += 128) xo[300 + c] = p[c];
}

// ---------------------------------------------------------------- fp32 GEMM pair, 128x128 tile, 8x8 acc:
// blockIdx.z selects {B,bias,C}; C[M,N] = A[M,K] @ B[N,K]^T + bias[N].
// M mult of 128, N mult of 128, K mult of 16. 256 threads.
// LDS transposed [k][row] stride 132. Inner: 4x ds_read_b128 + 64 fma
// (2x the FMA:LDS ratio of the old 128x64/8x4 kernel).
__global__ __launch_bounds__(256)
void gemm128(const float* __restrict__ A,
             const float* __restrict__ B0, const float* __restrict__ bias0, float* __restrict__ C0,
             const float* __restrict__ B1, const float* __restrict__ bias1, float* __restrict__ C1,
             int K, int lda, int ldb, int ldc) {
    const float* B    = blockIdx.z ? B1    : B0;
    const float* bias = blockIdx.z ? bias1 : bias0;
    float*       C    = blockIdx.z ? C1    : C0;

    __shared__ __align__(16) float As[16 * 132];
    __shared__ __align__(16) float Bs[16 * 132];
    const int tid  = threadIdx.x;
    const int bn   = blockIdx.x, bm = blockIdx.y;
    const int tj   = tid & 15, ti = tid >> 4;
    const int row2 = tid >> 1;               // 0..127
    const int k8   = (tid & 1) * 8;          // 0 or 8
    float acc[8][8] = {};

    for (int kt = 0; kt < K; kt += 16) {
        float4 a0 = *(const float4*)(A + (size_t)(bm * 128 + row2) * lda + kt + k8);
        float4 a1 = *(const float4*)(A + (size_t)(bm * 128 + row2) * lda + kt + k8 + 4);
        float4 b0 = *(const float4*)(B + (size_t)(bn * 128 + row2) * ldb + kt + k8);
        float4 b1 = *(const float4*)(B + (size_t)(bn * 128 + row2) * ldb + kt + k8 + 4);
        As[(k8 + 0) * 132 + row2] = a0.x; As[(k8 + 1) * 132 + row2] = a0.y;
        As[(k8 + 2) * 132 + row2] = a0.z; As[(k8 + 3) * 132 + row2] = a0.w;
        As[(k8 + 4) * 132 + row2] = a1.x; As[(k8 + 5) * 132 + row2] = a1.y;
        As[(k8 + 6) * 132 + row2] = a1.z; As[(k8 + 7) * 132 + row2] = a1.w;
        Bs[(k8 + 0) * 132 + row2] = b0.x; Bs[(k8 + 1) * 132 + row2] = b0.y;
        Bs[(k8 + 2) * 132 + row2] = b0.z; Bs[(k8 + 3) * 132 + row2] = b0.w;
        Bs[(k8 + 4) * 132 + row2] = b1.x; Bs[(k8 + 5) * 132 + row2] = b1.y;
        Bs[(k8 + 6) * 132 + row2] = b1.z; Bs[(k8 + 7) * 132 + row2] = b1.w;
        __syncthreads();
        #pragma unroll
        for (int k = 0; k < 16; ++k) {
            float4 x0 = *(const float4*)&As[k * 132 + ti * 8];
            float4 x1 = *(const float4*)&As[k * 132 + ti * 8 + 4];
            float4 y0 = *(const float4*)&Bs[k * 132 + tj * 8];
            float4 y1 = *(const float4*)&Bs[k * 132 + tj * 8 + 4];
            const float av[8] = {x0.x, x0.y, x0.z, x0.w, x1.x, x1.y, x1.z, x1.w};
            const float bv[8] = {y0.x, y0.y, y0.z, y0.w, y1.x, y1.y, y1.z, y1.w};
            #pragma unroll
            for (int i = 0; i < 8; ++i)
                #pragma unroll
                for (int j = 0; j < 8; ++j)
                    acc[i][j] = fmaf(av[i], bv[j], acc[i][j]);
        }
        __syncthreads();
    }
    const int n0 = bn * 128 + tj * 8;
    float bb[8];
    #pragma unroll
    for (int j = 0; j < 8; ++j) bb[j] = bias ? bias[n0 + j] : 0.f;
    #pragma unroll
    for (int i = 0; i < 8; ++i) {
        float4 o0, o1;
        o0.x = acc[i][0] + bb[0]; o0.y = acc[i][1] + bb[1];
        o0.z = acc[i][2] + bb[2]; o0.w = acc[i][3] + bb[3];
        o1.x = acc[i][4] + bb[4]; o1.y = acc[i][5] + bb[5];
        o1.z = acc[i][6] + bb[6]; o1.w = acc[i][7] + bb[7];
        float* cp = C + (size_t)(bm * 128 + ti * 8 + i) * ldc + n0;
        *(float4*)cp = o0; *(float4*)(cp + 4) = o1;
    }
}

// ---------------------------------------------------------------- persistent bidirectional LSTM layer
// R8 structure (proven best: 1465 us/layer) + 3-deep pipelined poll.
// 64 WGs x 576 threads (9 waves). Wave 0 = producer/finisher; waves 1..8 =
// k-chunk matvec. WGs [0,32): forward; [32,64): reverse. Each WG owns 16
// hidden units = 64 gate rows. lane = gate row.
__global__ __launch_bounds__(576)
void lstm_layer(const float* __restrict__ Zf, const float* __restrict__ Zr,
                const float* __restrict__ WhhF, const float* __restrict__ WhhR,
                unsigned long long* __restrict__ Hpair, // [SEQ][2*HID] (tag|h)
                float* __restrict__ Hout,               // [SEQ][2*HID] plain fp32
                unsigned tagBase) {
    const int dir = blockIdx.x >> 5;
    const int wg  = blockIdx.x & 31;
    const float* __restrict__ Z   = dir ? Zr   : Zf;
    const float* __restrict__ Whh = dir ? WhhR : WhhF;
    const int colOff = dir ? HID : 0;

    const int tid  = threadIdx.x;
    const int wave = tid >> 6;        // 0 = producer; 1..8 = k-chunks
    const int lane = tid & 63;        // local gate row 0..63
    const int g    = lane >> 4;       // gate 0..3 (i,f,g,o)
    const int jj   = lane & 15;       // local hidden unit 0..15
    const int grow = g * HID + wg * 16 + jj;   // row in Whh [2048 x 512]

    __shared__ float part[2][8 * 65];

    if (wave == 0) {
        // ---------------- producer / finisher wave ----------------
        float cval = 0.f;                 // cell state (lanes 0..15)
        float zin = Z[(size_t)(dir ? (SEQ - 1) : 0) * GATES + grow];
        for (int s = 0; s < SEQ; ++s) {
            const int t = dir ? (SEQ - 1 - s) : s;
            float znxt = 0.f;
            if (s + 1 < SEQ) {
                const int tn = dir ? (SEQ - 2 - s) : (s + 1);
                znxt = Z[(size_t)tn * GATES + grow];
            }
            __syncthreads();   // partials of step s are ready
            const float* pp = part[s & 1];
            float r = zin;
            #pragma unroll
            for (int c = 0; c < 8; ++c) r += pp[c * 65 + lane];
            float nl = (g == 2) ? tanh_fast(r) : sigm(r);
            float ig = __shfl(nl, jj);
            float fg = __shfl(nl, 16 + jj);
            float gg = __shfl(nl, 32 + jj);
            float og = __shfl(nl, 48 + jj);
            if (lane < 16) {
                cval = fg * cval + ig * gg;
                float hv = og * tanh_fast(cval);
                const size_t oidx = (size_t)t * (2 * HID) + colOff + wg * 16 + lane;
                unsigned long long pk = ((unsigned long long)(tagBase + (unsigned)s) << 32)
                                      | (unsigned long long)__float_as_uint(hv);
                __hip_atomic_store(Hpair + oidx, pk, __ATOMIC_RELAXED, __HIP_MEMORY_SCOPE_AGENT);
                Hout[oidx] = hv;   // plain fp32 for downstream GEMMs (off critical path)
            }
            zin = znxt;
        }
    } else {
        // ---------------- matvec waves (k-chunks) ----------------
        const int kc = wave - 1;          // k-chunk 0..7 (h[64*kc .. +64))
        float w[64];
        {
            const float4* wp = (const float4*)(Whh + (size_t)grow * HID + kc * 64);
            #pragma unroll
            for (int q = 0; q < 16; ++q) {
                float4 v = wp[q];
                w[4 * q] = v.x; w[4 * q + 1] = v.y; w[4 * q + 2] = v.z; w[4 * q + 3] = v.w;
            }
        }
        for (int s = 0; s < SEQ; ++s) {
            const int t = dir ? (SEQ - 1 - s) : s;
            float acc = 0.f;
            if (s > 0) {
                const int tp = dir ? (t + 1) : (t - 1);
                const unsigned expTag = tagBase + (unsigned)s - 1u;
                const unsigned long long* hp =
                    Hpair + (size_t)tp * (2 * HID) + colOff + kc * 64 + lane;
                // 3-deep pipelined poll: oldest-of-three rotation; compiler
                // waits vmcnt(2) -> check period ~ latency/3
                unsigned long long va, vb, vc, v;
                va = __hip_atomic_load(hp, __ATOMIC_RELAXED, __HIP_MEMORY_SCOPE_AGENT);
                vb = __hip_atomic_load(hp, __ATOMIC_RELAXED, __HIP_MEMORY_SCOPE_AGENT);
                for (;;) {
                    vc = __hip_atomic_load(hp, __ATOMIC_RELAXED, __HIP_MEMORY_SCOPE_AGENT);
                    if (__all((unsigned)(va >> 32) == expTag)) { v = va; break; }
                    va = vb; vb = vc;
                }
                float hv = __uint_as_float((unsigned)v);   // h[64*kc + lane]
                float a0 = 0.f, a1 = 0.f, a2 = 0.f, a3 = 0.f;
                #pragma unroll
                for (int m = 0; m < 64; m += 4) {
                    a0 = fmaf(w[m + 0], bcast(hv, m + 0), a0);
                    a1 = fmaf(w[m + 1], bcast(hv, m + 1), a1);
                    a2 = fmaf(w[m + 2], bcast(hv, m + 2), a2);
                    a3 = fmaf(w[m + 3], bcast(hv, m + 3), a3);
                }
                acc = (a0 + a1) + (a2 + a3);
            }
            part[s & 1][kc * 65 + lane] = acc;
            __syncthreads();
        }
    }
}

// ---------------------------------------------------------------- pairwise MLP scores
// 32x32 output tile, 256 threads, 2x2 micro-tile per thread (amortizes LDS
// reads 2.4x on the LDS-issue-bound inner loop). LDS stride 256 with XOR
// swizzle on ((row>>1)&7) so both rows of a micro-pair share the swizzle;
// a-reads and b-reads are both <=2-way (free). w2 read via wave-uniform
// global loads (SMEM path), not LDS.
__global__ __launch_bounds__(256)
void pairwise_kernel(const float* __restrict__ Ah, const float* __restrict__ Bd,
                     const float* __restrict__ w2, const float* __restrict__ b2,
                     float* __restrict__ out) {
    __shared__ __align__(16) float at[32 * 256];
    __shared__ __align__(16) float bt[32 * 256];
    const int tid = threadIdx.x;
    const int i0 = blockIdx.y * 32, j0 = blockIdx.x * 32;
    // fill: pass p = row p; lane m = column; swizzled column block
    for (int p = 0; p < 32; ++p) {
        int m = tid;
        int sw = ((m >> 2) ^ ((p >> 1) & 7)) * 4 + (m & 3);
        at[p * 256 + sw] = Ah[(size_t)(i0 + p) * 256 + m];
        bt[p * 256 + sw] = Bd[(size_t)(j0 + p) * 256 + m];
    }
    __syncthreads();
    const int tj = tid & 15, ti = tid >> 4;
    const int qa4 = (ti & 7) * 4;            // swizzle key for rows 2ti,2ti+1
    const int qb4 = (tj & 7) * 4;
    const float* a0p = &at[(2 * ti) * 256];
    const float* a1p = a0p + 256;
    const float* b0p = &bt[(2 * tj) * 256];
    const float* b1p = b0p + 256;
    const float bias = b2[0];
    float acc00 = bias, acc01 = bias, acc10 = bias, acc11 = bias;
    #pragma unroll 4
    for (int m = 0; m < 256; m += 4) {
        const int ca = m ^ qa4, cb = m ^ qb4;
        float4 a0 = *(const float4*)&a0p[ca];
        float4 a1 = *(const float4*)&a1p[ca];
        float4 b0 = *(const float4*)&b0p[cb];
        float4 b1 = *(const float4*)&b1p[cb];
        float4 w4 = *(const float4*)&w2[m];   // wave-uniform -> scalar load
        acc00 += tanh_fast(a0.x + b0.x) * w4.x; acc01 += tanh_fast(a0.x + b1.x) * w4.x;
        acc10 += tanh_fast(a1.x + b0.x) * w4.x; acc11 += tanh_fast(a1.x + b1.x) * w4.x;
        acc00 += tanh_fast(a0.y + b0.y) * w4.y; acc01 += tanh_fast(a0.y + b1.y) * w4.y;
        acc10 += tanh_fast(a1.y + b0.y) * w4.y; acc11 += tanh_fast(a1.y + b1.y) * w4.y;
        acc00 += tanh_fast(a0.z + b0.z) * w4.z; acc01 += tanh_fast(a0.z + b1.z) * w4.z;
        acc10 += tanh_fast(a1.z + b0.z) * w4.z; acc11 += tanh_fast(a1.z + b1.z) * w4.z;
        acc00 += tanh_fast(a0.w + b0.w) * w4.w; acc01 += tanh_fast(a0.w + b1.w) * w4.w;
        acc10 += tanh_fast(a1.w + b0.w) * w4.w; acc11 += tanh_fast(a1.w + b1.w) * w4.w;
    }
    float* o0 = out + (size_t)(i0 + 2 * ti) * 1024 + j0 + 2 * tj;
    float* o1 = o0 + 1024;
    float2 r0; r0.x = acc00; r0.y = acc01;
    float2 r1; r1.x = acc10; r1.y = acc11;
    *(float2*)o0 = r0;
    *(float2*)o1 = r1;
}

// ---------------------------------------------------------------- launch
extern "C" void kernel_launch(void* const* d_in, const int* in_sizes, int n_in,
                              void* d_out, int out_size, void* d_ws, size_t ws_size,
                              hipStream_t stream) {
    const int*   wi    = (const int*)  d_in[0];
    const int*   pi    = (const int*)  d_in[1];
    const float* we    = (const float*)d_in[2];
    const float* pe    = (const float*)d_in[3];
    const float* wih0f = (const float*)d_in[4];
    const float* whh0f = (const float*)d_in[5];
    const float* b0f   = (const float*)d_in[6];
    const float* wih0r = (const float*)d_in[7];
    const float* whh0r = (const float*)d_in[8];
    const float* b0r   = (const float*)d_in[9];
    const float* wih1f = (const float*)d_in[10];
    const float* whh1f = (const float*)d_in[11];
    const float* b1f   = (const float*)d_in[12];
    const float* wih1r = (const float*)d_in[13];
    const float* whh1r = (const float*)d_in[14];
    const float* b1r   = (const float*)d_in[15];
    const float* W1    = (const float*)d_in[16];
    const float* bmlp1 = (const float*)d_in[17];
    const float* w2    = (const float*)d_in[18];
    const float* b2    = (const float*)d_in[19];
    float* out = (float*)d_out;

    char* wsb = (char*)d_ws;
    float* x  = (float*)(wsb + 512);          // 1024*400
    float* zA = x  + (size_t)1024 * 400;      // 1024*2048
    float* zB = zA + (size_t)1024 * 2048;     // 1024*2048
    float* h0 = zB + (size_t)1024 * 2048;     // 1024*1024
    float* h1 = h0 + (size_t)1024 * 1024;     // 1024*1024
    float* aH = h1 + (size_t)1024 * 1024;     // 1024*256
    float* bD = aH + (size_t)1024 * 256;      // 1024*256
    unsigned long long* Hpair = (unsigned long long*)(bD + (size_t)1024 * 256); // 1024*1024 u64

    embed_kernel<<<dim3(1024), dim3(128), 0, stream>>>(wi, pi, we, pe, x);

    // layer-0 input projections (both directions): [1024,400]@[2048,400]^T
    gemm128<<<dim3(16, 8, 2), dim3(256), 0, stream>>>(
        x, wih0f, b0f, zA, wih0r, b0r, zB, 400, 400, 400, 2048);

    lstm_layer<<<dim3(64), dim3(576), 0, stream>>>(zA, zB, whh0f, whh0r, Hpair, h0, 1u);

    // layer-1 input projections (both directions): [1024,1024]@[2048,1024]^T
    gemm128<<<dim3(16, 8, 2), dim3(256), 0, stream>>>(
        h0, wih1f, b1f, zA, wih1r, b1r, zB, 1024, 1024, 1024, 2048);

    lstm_layer<<<dim3(64), dim3(576), 0, stream>>>(zA, zB, whh1f, whh1r, Hpair, h1, 8192u);

    // head/dep projections (one launch): [1024,1024]@[256,1024]^T (bmlp1 folded into aH)
    gemm128<<<dim3(2, 8, 2), dim3(256), 0, stream>>>(
        h1, W1, bmlp1, aH, W1 + 1024, nullptr, bD, 1024, 1024, 2048, 256);

    pairwise_kernel<<<dim3(32, 32), dim3(256), 0, stream>>>(aH, bD, w2, b2, out);
}

// Round 7
// 3834.624 us; speedup vs baseline: 1.0422x; 1.0302x over previous
//
#include <hip/hip_runtime.h>
#include <hip/hip_bf16.h>

#define HID   512
#define SEQ   1024
#define GATES 2048       // 4*HID

// ---------------------------------------------------------------- helpers
__device__ __forceinline__ float sigm(float x) {
    return 1.f / (1.f + __expf(-x));
}
__device__ __forceinline__ float tanh_fast(float x) {
    float ax = fabsf(x);
    float e  = __expf(-2.f * ax);
    float t  = (1.f - e) * __builtin_amdgcn_rcpf(1.f + e);
    return copysignf(t, x);
}
__device__ __forceinline__ float bcast(float v, int l) {
    return __uint_as_float((unsigned)__builtin_amdgcn_readlane((int)__float_as_uint(v), l));
}

// ---------------------------------------------------------------- embedding
__global__ void embed_kernel(const int* __restrict__ wi, const int* __restrict__ pi,
                             const float* __restrict__ we, const float* __restrict__ pe,
                             float* __restrict__ x) {
    int i = blockIdx.x;          // token 0..1023
    int t = threadIdx.x;         // 128 threads
    const float* w = we + (size_t)wi[i] * 300;
    const float* p = pe + (size_t)pi[i] * 100;
    float* xo = x + (size_t)i * 400;
    for (int c = t; c < 300; c += 128) xo[c]       = w[c];
    for (int c = t; c < 100; c += 128) xo[300 + c] = p[c];
}

// ---------------------------------------------------------------- fp32 GEMM pair, 128x64 tile (R1-proven):
// blockIdx.z selects {B,bias,C}; C[M,N] = A[M,K] @ B[N,K]^T + bias[N].
__global__ __launch_bounds__(256)
void gemm_bias2(const float* __restrict__ A,
                const float* __restrict__ B0, const float* __restrict__ bias0, float* __restrict__ C0,
                const float* __restrict__ B1, const float* __restrict__ bias1, float* __restrict__ C1,
                int M, int N, int K, int lda, int ldb, int ldc) {
    const float* B    = blockIdx.z ? B1    : B0;
    const float* bias = blockIdx.z ? bias1 : bias0;
    float*       C    = blockIdx.z ? C1    : C0;

    __shared__ __align__(16) float As[16 * 132];
    __shared__ __align__(16) float Bs[16 * 68];
    const int tid  = threadIdx.x;
    const int bn   = blockIdx.x, bm = blockIdx.y;
    const int tj   = tid & 15, ti = tid >> 4;
    const int arow = tid >> 1;               // 0..127
    const int ak8  = (tid & 1) * 8;          // 0 or 8
    const int brow = tid >> 2;               // 0..63
    const int bk4  = (tid & 3) * 4;          // 0,4,8,12
    float acc[8][4] = {};

    for (int kt = 0; kt < K; kt += 16) {
        float4 a0 = *(const float4*)(A + (size_t)(bm * 128 + arow) * lda + kt + ak8);
        float4 a1 = *(const float4*)(A + (size_t)(bm * 128 + arow) * lda + kt + ak8 + 4);
        float4 bv = *(const float4*)(B + (size_t)(bn * 64 + brow) * ldb + kt + bk4);
        As[(ak8 + 0) * 132 + arow] = a0.x; As[(ak8 + 1) * 132 + arow] = a0.y;
        As[(ak8 + 2) * 132 + arow] = a0.z; As[(ak8 + 3) * 132 + arow] = a0.w;
        As[(ak8 + 4) * 132 + arow] = a1.x; As[(ak8 + 5) * 132 + arow] = a1.y;
        As[(ak8 + 6) * 132 + arow] = a1.z; As[(ak8 + 7) * 132 + arow] = a1.w;
        Bs[(bk4 + 0) * 68 + brow] = bv.x; Bs[(bk4 + 1) * 68 + brow] = bv.y;
        Bs[(bk4 + 2) * 68 + brow] = bv.z; Bs[(bk4 + 3) * 68 + brow] = bv.w;
        __syncthreads();
        #pragma unroll
        for (int k = 0; k < 16; ++k) {
            float4 x0 = *(const float4*)&As[k * 132 + ti * 8];
            float4 x1 = *(const float4*)&As[k * 132 + ti * 8 + 4];
            float4 b4 = *(const float4*)&Bs[k * 68 + tj * 4];
            const float av[8] = {x0.x, x0.y, x0.z, x0.w, x1.x, x1.y, x1.z, x1.w};
            #pragma unroll
            for (int i = 0; i < 8; ++i) {
                acc[i][0] = fmaf(av[i], b4.x, acc[i][0]);
                acc[i][1] = fmaf(av[i], b4.y, acc[i][1]);
                acc[i][2] = fmaf(av[i], b4.z, acc[i][2]);
                acc[i][3] = fmaf(av[i], b4.w, acc[i][3]);
            }
        }
        __syncthreads();
    }
    const int n0 = bn * 64 + tj * 4;
    float bb0 = 0.f, bb1 = 0.f, bb2 = 0.f, bb3 = 0.f;
    if (bias) { bb0 = bias[n0]; bb1 = bias[n0 + 1]; bb2 = bias[n0 + 2]; bb3 = bias[n0 + 3]; }
    #pragma unroll
    for (int i = 0; i < 8; ++i) {
        float4 o;
        o.x = acc[i][0] + bb0; o.y = acc[i][1] + bb1;
        o.z = acc[i][2] + bb2; o.w = acc[i][3] + bb3;
        *(float4*)(C + (size_t)(bm * 128 + ti * 8 + i) * ldc + n0) = o;
    }
}

// ---------------------------------------------------------------- persistent bidirectional LSTM layer
// R12 = R8 structure (proven 1465 us/layer) + two copy-free micro-opts:
//  (1) 4-slot unrolled poll (NO register rotation -> checks wait vmcnt(3),
//      check period ~ lat/4; R6's 3-deep rotation forced vmcnt(0) = regression).
//  (2) barrier-free step loop: per-wave LDS flags (release by matvec waves,
//      acquire-poll by producer) instead of per-step __syncthreads, so matvec
//      waves never wait for sibling chunks. Double-buffered part[] is safe:
//      a wave reaches step s only after observing h(s-1), which implies the
//      producer finished reading part[(s-2)&1] == part[s&1].
// 64 WGs x 576 threads (9 waves). Wave 0 = producer/finisher; waves 1..8 =
// k-chunk matvec. WGs [0,32): forward; [32,64): reverse.
__global__ __launch_bounds__(576)
void lstm_layer(const float* __restrict__ Zf, const float* __restrict__ Zr,
                const float* __restrict__ WhhF, const float* __restrict__ WhhR,
                unsigned long long* __restrict__ Hpair, // [SEQ][2*HID] (tag|h)
                float* __restrict__ Hout,               // [SEQ][2*HID] plain fp32
                unsigned tagBase) {
    const int dir = blockIdx.x >> 5;
    const int wg  = blockIdx.x & 31;
    const float* __restrict__ Z   = dir ? Zr   : Zf;
    const float* __restrict__ Whh = dir ? WhhR : WhhF;
    const int colOff = dir ? HID : 0;

    const int tid  = threadIdx.x;
    const int wave = tid >> 6;        // 0 = producer; 1..8 = k-chunks
    const int lane = tid & 63;        // local gate row 0..63
    const int g    = lane >> 4;       // gate 0..3 (i,f,g,o)
    const int jj   = lane & 15;       // local hidden unit 0..15
    const int grow = g * HID + wg * 16 + jj;   // row in Whh [2048 x 512]

    __shared__ float part[2][8 * 65];
    __shared__ unsigned flags[8];     // per-matvec-wave completed-step counter

    if (tid < 8) flags[tid] = 0u;
    __syncthreads();                  // one-time init barrier (only barrier in kernel)

    if (wave == 0) {
        // ---------------- producer / finisher wave ----------------
        float cval = 0.f;                 // cell state (lanes 0..15)
        float zin = Z[(size_t)(dir ? (SEQ - 1) : 0) * GATES + grow];
        const int fi = lane & 7;
        for (int s = 0; s < SEQ; ++s) {
            const int t = dir ? (SEQ - 1 - s) : s;
            float znxt = 0.f;
            if (s + 1 < SEQ) {
                const int tn = dir ? (SEQ - 2 - s) : (s + 1);
                znxt = Z[(size_t)tn * GATES + grow];
            }
            // wait for all 8 partials of step s (LDS flag poll; acquire)
            const unsigned need = (unsigned)s + 1u;
            for (;;) {
                unsigned v = __hip_atomic_load(&flags[fi], __ATOMIC_ACQUIRE,
                                               __HIP_MEMORY_SCOPE_WORKGROUP);
                if (__all(v >= need)) break;
            }
            const float* pp = part[s & 1];
            float r = zin;
            #pragma unroll
            for (int c = 0; c < 8; ++c) r += pp[c * 65 + lane];
            float nl = (g == 2) ? tanh_fast(r) : sigm(r);
            float ig = __shfl(nl, jj);
            float fg = __shfl(nl, 16 + jj);
            float gg = __shfl(nl, 32 + jj);
            float og = __shfl(nl, 48 + jj);
            if (lane < 16) {
                cval = fg * cval + ig * gg;
                float hv = og * tanh_fast(cval);
                const size_t oidx = (size_t)t * (2 * HID) + colOff + wg * 16 + lane;
                unsigned long long pk = ((unsigned long long)(tagBase + (unsigned)s) << 32)
                                      | (unsigned long long)__float_as_uint(hv);
                __hip_atomic_store(Hpair + oidx, pk, __ATOMIC_RELAXED, __HIP_MEMORY_SCOPE_AGENT);
                Hout[oidx] = hv;   // plain fp32 for downstream GEMMs (off critical path)
            }
            zin = znxt;
        }
    } else {
        // ---------------- matvec waves (k-chunks) ----------------
        const int kc = wave - 1;          // k-chunk 0..7 (h[64*kc .. +64))
        float w[64];
        {
            const float4* wp = (const float4*)(Whh + (size_t)grow * HID + kc * 64);
            #pragma unroll
            for (int q = 0; q < 16; ++q) {
                float4 v = wp[q];
                w[4 * q] = v.x; w[4 * q + 1] = v.y; w[4 * q + 2] = v.z; w[4 * q + 3] = v.w;
            }
        }
        for (int s = 0; s < SEQ; ++s) {
            const int t = dir ? (SEQ - 1 - s) : s;
            float acc = 0.f;
            if (s > 0) {
                const int tp = dir ? (t + 1) : (t - 1);
                const unsigned expTag = tagBase + (unsigned)s - 1u;
                const unsigned long long* hp =
                    Hpair + (size_t)tp * (2 * HID) + colOff + kc * 64 + lane;
                // 4-slot copy-free pipelined poll: 4 loads in flight, no
                // register rotation -> each check waits vmcnt(3); period ~lat/4
                #define LD() __hip_atomic_load(hp, __ATOMIC_RELAXED, __HIP_MEMORY_SCOPE_AGENT)
                #define OK(x) __all((unsigned)((x) >> 32) == expTag)
                unsigned long long va, vb, vc, vd, v;
                va = LD(); vb = LD(); vc = LD();
                for (;;) {
                    vd = LD(); if (OK(va)) { v = va; break; }
                    va = LD(); if (OK(vb)) { v = vb; break; }
                    vb = LD(); if (OK(vc)) { v = vc; break; }
                    vc = LD(); if (OK(vd)) { v = vd; break; }
                }
                #undef LD
                #undef OK
                float hv = __uint_as_float((unsigned)v);   // h[64*kc + lane]
                float a0 = 0.f, a1 = 0.f, a2 = 0.f, a3 = 0.f;
                #pragma unroll
                for (int m = 0; m < 64; m += 4) {
                    a0 = fmaf(w[m + 0], bcast(hv, m + 0), a0);
                    a1 = fmaf(w[m + 1], bcast(hv, m + 1), a1);
                    a2 = fmaf(w[m + 2], bcast(hv, m + 2), a2);
                    a3 = fmaf(w[m + 3], bcast(hv, m + 3), a3);
                }
                acc = (a0 + a1) + (a2 + a3);
            }
            part[s & 1][kc * 65 + lane] = acc;
            // publish: release orders the part[] write before the flag
            if (lane == 0)
                __hip_atomic_store(&flags[kc], (unsigned)s + 1u, __ATOMIC_RELEASE,
                                   __HIP_MEMORY_SCOPE_WORKGROUP);
        }
    }
}

// ---------------------------------------------------------------- pairwise MLP scores (R1-proven)
__global__ __launch_bounds__(256)
void pairwise_kernel(const float* __restrict__ Ah, const float* __restrict__ Bd,
                     const float* __restrict__ w2, const float* __restrict__ b2,
                     float* __restrict__ out) {
    __shared__ __align__(16) float at[16 * 260];
    __shared__ __align__(16) float bt[16 * 260];
    __shared__ __align__(16) float wl[256];
    const int tid = threadIdx.x;
    const int i0 = blockIdx.y * 16, j0 = blockIdx.x * 16;
    for (int u = tid; u < 16 * 256; u += 256) {
        int r = u >> 8, m = u & 255;
        at[r * 260 + m] = Ah[(size_t)(i0 + r) * 256 + m];
        bt[r * 260 + m] = Bd[(size_t)(j0 + r) * 256 + m];
    }
    wl[tid] = w2[tid];
    __syncthreads();
    const int tj = tid & 15, ti = tid >> 4;
    float acc = b2[0];
    #pragma unroll 2
    for (int m = 0; m < 256; m += 4) {
        float4 a4 = *(const float4*)&at[ti * 260 + m];
        float4 b4 = *(const float4*)&bt[tj * 260 + m];
        float4 w4 = *(const float4*)&wl[m];
        acc += tanh_fast(a4.x + b4.x) * w4.x;
        acc += tanh_fast(a4.y + b4.y) * w4.y;
        acc += tanh_fast(a4.z + b4.z) * w4.z;
        acc += tanh_fast(a4.w + b4.w) * w4.w;
    }
    out[(size_t)(i0 + ti) * 1024 + (j0 + tj)] = acc;
}

// ---------------------------------------------------------------- launch
extern "C" void kernel_launch(void* const* d_in, const int* in_sizes, int n_in,
                              void* d_out, int out_size, void* d_ws, size_t ws_size,
                              hipStream_t stream) {
    const int*   wi    = (const int*)  d_in[0];
    const int*   pi    = (const int*)  d_in[1];
    const float* we    = (const float*)d_in[2];
    const float* pe    = (const float*)d_in[3];
    const float* wih0f = (const float*)d_in[4];
    const float* whh0f = (const float*)d_in[5];
    const float* b0f   = (const float*)d_in[6];
    const float* wih0r = (const float*)d_in[7];
    const float* whh0r = (const float*)d_in[8];
    const float* b0r   = (const float*)d_in[9];
    const float* wih1f = (const float*)d_in[10];
    const float* whh1f = (const float*)d_in[11];
    const float* b1f   = (const float*)d_in[12];
    const float* wih1r = (const float*)d_in[13];
    const float* whh1r = (const float*)d_in[14];
    const float* b1r   = (const float*)d_in[15];
    const float* W1    = (const float*)d_in[16];
    const float* bmlp1 = (const float*)d_in[17];
    const float* w2    = (const float*)d_in[18];
    const float* b2    = (const float*)d_in[19];
    float* out = (float*)d_out;

    char* wsb = (char*)d_ws;
    float* x  = (float*)(wsb + 512);          // 1024*400
    float* zA = x  + (size_t)1024 * 400;      // 1024*2048
    float* zB = zA + (size_t)1024 * 2048;     // 1024*2048
    float* h0 = zB + (size_t)1024 * 2048;     // 1024*1024
    float* h1 = h0 + (size_t)1024 * 1024;     // 1024*1024
    float* aH = h1 + (size_t)1024 * 1024;     // 1024*256
    float* bD = aH + (size_t)1024 * 256;      // 1024*256
    unsigned long long* Hpair = (unsigned long long*)(bD + (size_t)1024 * 256); // 1024*1024 u64

    embed_kernel<<<dim3(1024), dim3(128), 0, stream>>>(wi, pi, we, pe, x);

    // layer-0 input projections (both directions): [1024,400]@[2048,400]^T
    gemm_bias2<<<dim3(32, 8, 2), dim3(256), 0, stream>>>(
        x, wih0f, b0f, zA, wih0r, b0r, zB, 1024, 2048, 400, 400, 400, 2048);

    lstm_layer<<<dim3(64), dim3(576), 0, stream>>>(zA, zB, whh0f, whh0r, Hpair, h0, 1u);

    // layer-1 input projections (both directions): [1024,1024]@[2048,1024]^T
    gemm_bias2<<<dim3(32, 8, 2), dim3(256), 0, stream>>>(
        h0, wih1f, b1f, zA, wih1r, b1r, zB, 1024, 2048, 1024, 1024, 1024, 2048);

    lstm_layer<<<dim3(64), dim3(576), 0, stream>>>(zA, zB, whh1f, whh1r, Hpair, h1, 8192u);

    // head/dep projections (one launch): [1024,1024]@[256,1024]^T (bmlp1 folded into aH)
    gemm_bias2<<<dim3(4, 8, 2), dim3(256), 0, stream>>>(
        h1, W1, bmlp1, aH, W1 + 1024, nullptr, bD, 1024, 256, 1024, 1024, 2048, 256);

    pairwise_kernel<<<dim3(64, 64), dim3(256), 0, stream>>>(aH, bD, w2, b2, out);
}